// Round 28
// baseline (4660.300 us; speedup 1.0000x reference)
//
#include <hip/hip_runtime.h>

// Round 28: dispatch-count attack. 123 -> 55 dispatches via full-K fused kernels:
//  k_lstm  = gate-gemm + LSTM cell in one kernel (no partial buffers)
//  k_post  = relfeat tmp gemms + fproj + srcadd + logits per-b in LDS
//  k_locenc2 = per-b single-pass enc streaming with 17 step-accumulators

#define NB 64
#define NL 81
#define ND2 512
#define NS 17
#define NC 256
#define NV 13042
#define NH 512
#define NE 80
#define NP 60
#define NF 178
#define NKX 652
#define NOUT (NB*NS*(2+NC))   // 280704 floats

// ws layout (floats)
#define OFF_XSTAT 0            // [17][652][64] = 709376
#define OFF_AL    709376       // (unused scratch, reserved)
#define OFF_H0    797504       // [2][512][64]
#define OFF_C0    863040       // [512][64]
#define OFF_C1    895808       // [512][64]
#define OFF_OT    928576       // [2][513][64], row 512 = 1.0
#define WS_END    994240

__device__ __forceinline__ float sigm(float x) { return 1.0f / (1.0f + expf(-x)); }

// ---------------- outputs 0/1 ----------------
__global__ void k_out01(const int* cand, const int* teacher, float* out) {
    int i = blockIdx.x * 256 + threadIdx.x;
    if (i >= NB * NS) return;
    int tv = teacher[i];
    int mi = 0;
    const int* cr = cand + (long long)i * NC;
    for (int c = 0; c < NC; ++c) {
        if (cr[c] == tv) { mi = c; break; }
    }
    out[i] = (float)tv;
    out[NB * NS + i] = (float)mi;
}

// ---------------- init state: zeros + ones-rows of both OT buffers ----------------
__global__ void k_init(float* ws) {
    long long n = WS_END - OFF_H0;
    for (long long i = (long long)blockIdx.x * 256 + threadIdx.x; i < n;
         i += (long long)gridDim.x * 256) {
        long long a = OFF_H0 + i;
        float v = 0.0f;
        if (a >= OFF_OT) {
            long long r = (a - OFF_OT) % 32832;   // 513*64 per buffer
            if ((r >> 6) == 512) v = 1.0f;
        }
        ws[a] = v;
    }
}

// ---------------- loc_enc for ALL steps, one block per b ----------------
__global__ void k_locenc2(const int* loc_idxs, const float* MA, const float* enc,
                          float* xstat) {
    int b = blockIdx.x, t = threadIdx.x;
    __shared__ float sMA[NL * NL];   // 6561
    __shared__ float sAL[NS * NL];   // 1377 (unnormalized)
    __shared__ float sinv[NS];
    __shared__ int loc[NL];
    if (t < NL) loc[t] = loc_idxs[b * NL + t];
    for (int i = t; i < NL * NL; i += 256) sMA[i] = MA[i];
    __syncthreads();
    for (int idx = t; idx < NS * NL; idx += 256) {
        int s = idx / NL, m = idx - s * NL;
        float a = 0.0f;
        for (int l = 0; l < NL; ++l)
            if (loc[l] == s || loc[l] == -2) a += sMA[l * NL + m];
        sAL[idx] = a;
    }
    __syncthreads();
    if (t < NS) {
        float sm = 0.0f;
        for (int m = 0; m < NL; ++m) sm += sAL[t * NL + m];
        sinv[t] = 1.0f / (sm + 1e-5f);
    }
    __syncthreads();
    float acc0[NS], acc1[NS];
#pragma unroll
    for (int s = 0; s < NS; ++s) { acc0[s] = 0.0f; acc1[s] = 0.0f; }
    const float* eb = enc + (long long)b * NL * ND2;
    for (int m = 0; m < NL; ++m) {
        float e0 = eb[m * ND2 + t];
        float e1 = eb[m * ND2 + t + 256];
#pragma unroll
        for (int s = 0; s < NS; ++s) {
            float a = sAL[s * NL + m];
            acc0[s] += a * e0;
            acc1[s] += a * e1;
        }
    }
#pragma unroll
    for (int s = 0; s < NS; ++s) {
        xstat[((long long)s * NKX + t) * 64 + b] = acc0[s] * sinv[s];
        xstat[((long long)s * NKX + t + 256) * 64 + b] = acc1[s] * sinv[s];
    }
}

// ---------------- order_emb + power_emb -> xstat rows [512,652) ----------------
__global__ void k_embpow(const int* teacher, const int* power,
                         const float* oemb, const float* feats,
                         const float* oflw, const float* oflb,
                         const float* plw, const float* plb,
                         float* xstat) {
    int s = blockIdx.x, b = blockIdx.y, t = threadIdx.x;
    __shared__ float lf[NF];
    int tf = (s > 0) ? teacher[b * NS + (s - 1)] : 0;
    if (t < NF) lf[t] = feats[(long long)tf * NF + t];
    __syncthreads();
    if (t < NE) {
        float v = 0.0f;
        if (s > 0) {
            v = oemb[(long long)tf * NE + t] + oflb[t];
            for (int f = 0; f < NF; ++f) v += lf[f] * oflw[f * NE + t];
        }
        xstat[((long long)s * NKX + 512 + t) * 64 + b] = v;
    } else if (t < NE + NP) {
        int p = t - NE;
        int pw = power[b * NS + s];
        if (pw < 0) pw = 0;
        xstat[((long long)s * NKX + 592 + p) * 64 + b] = plw[pw * NP + p] + plb[p];
    }
}

// ---------------- fused LSTM layer: 4-gate full-K gemm + cell ----------------
// grid 128 blocks x 512 threads. tid = kh*256 + jl*64 + b (wave-uniform kh,jl).
// kh=0: xA (KA rows, weights wA stride KA). kh=1: xB (512 rows, wB stride 512).
__global__ void k_lstm(const float* xA, int KA, const float* xB,
                       const float* wA, const float* wB,
                       const float* bih, const float* bhh,
                       float* cT, float* hout) {
    __shared__ float part[2][4][4][64];
    int tid = threadIdx.x;
    int b = tid & 63, jl = (tid >> 6) & 3, kh = tid >> 8;
    int j = blockIdx.x * 4 + jl;
    const float* x = kh ? xB : xA;
    const float* w = kh ? wB : wA;
    int K = kh ? 512 : KA;
    const float4* w0 = (const float4*)(w + (long long)j * K);
    const float4* w1 = (const float4*)(w + (long long)(512 + j) * K);
    const float4* w2 = (const float4*)(w + (long long)(1024 + j) * K);
    const float4* w3 = (const float4*)(w + (long long)(1536 + j) * K);
    float a0 = 0.f, a1 = 0.f, a2 = 0.f, a3 = 0.f;
    int K4 = K >> 2;
    for (int k4 = 0; k4 < K4; ++k4) {
        int k = k4 << 2;
        float x0 = x[(k + 0) * 64 + b];
        float x1 = x[(k + 1) * 64 + b];
        float x2 = x[(k + 2) * 64 + b];
        float x3 = x[(k + 3) * 64 + b];
        float4 q0 = w0[k4], q1 = w1[k4], q2 = w2[k4], q3 = w3[k4];
        a0 += q0.x * x0 + q0.y * x1 + q0.z * x2 + q0.w * x3;
        a1 += q1.x * x0 + q1.y * x1 + q1.z * x2 + q1.w * x3;
        a2 += q2.x * x0 + q2.y * x1 + q2.z * x2 + q2.w * x3;
        a3 += q3.x * x0 + q3.y * x1 + q3.z * x2 + q3.w * x3;
    }
    part[kh][jl][0][b] = a0;
    part[kh][jl][1][b] = a1;
    part[kh][jl][2][b] = a2;
    part[kh][jl][3][b] = a3;
    __syncthreads();
    if (kh == 0) {
        float gi = a0 + part[1][jl][0][b] + bih[j] + bhh[j];
        float gf = a1 + part[1][jl][1][b] + bih[512 + j] + bhh[512 + j];
        float gg = a2 + part[1][jl][2][b] + bih[1024 + j] + bhh[1024 + j];
        float go = a3 + part[1][jl][3][b] + bih[1536 + j] + bhh[1536 + j];
        float c = cT[j * 64 + b];
        float cn = sigm(gf) * c + sigm(gi) * tanhf(gg);
        float h = sigm(go) * tanhf(cn);
        cT[j * 64 + b] = cn;
        hout[j * 64 + b] = h;
    }
}

// ---------------- fused post: tmp gemms + fproj + srcadd + logits, per-b ----------------
__global__ void k_post(const float* otcur, const float* enc,
                       const float* rsw, const float* rsb,
                       const float* rdw, const float* rdb,
                       const float* esb, const float* edb,
                       const float* odww, const float* odwb,
                       const float* odbw, const float* odbb,
                       const float* cemb, const float* feats,
                       const int* cand, const int* osrc, const int* odst,
                       int s, float* out) {
    int b = blockIdx.x, t = threadIdx.x;
    __shared__ float oh[513];
    __shared__ float tmpc[2][512];
    __shared__ float lfp[180];
    __shared__ float sb[2];
    __shared__ float sa[NL];
    __shared__ float da[NL];
    for (int d = t; d < 513; d += 256) oh[d] = otcur[d * 64 + b];
    __syncthreads();
#pragma unroll
    for (int r = 0; r < 4; ++r) {
        int idx = t + 256 * r;              // 0..1023
        int which = idx >> 9, d = idx & 511;
        const float* w = (which ? rdw : rsw) + (long long)d * 513;
        float acc = 0.0f;
        for (int c = 0; c < 513; ++c) acc += w[c] * oh[c];
        tmpc[which][d] = acc;
    }
    if (t < NF) {
        const float* w = odww + (long long)t * 512;
        float acc = odbw[t];
        for (int h = 0; h < 512; ++h) acc += w[h] * oh[h];
        lfp[t] = acc;
    } else if (t == NF) {
        float acc = odbb[0];
        for (int h = 0; h < 512; ++h) acc += odwb[h] * oh[h];
        lfp[NF] = acc;
    } else if (t == 179) {
        float acc = 0.0f;
        for (int c = 0; c < 513; ++c) acc += (rsb[c] + esb[c]) * oh[c];
        sb[0] = acc;
    } else if (t == 180) {
        float acc = 0.0f;
        for (int c = 0; c < 513; ++c) acc += (rdb[c] + edb[c]) * oh[c];
        sb[1] = acc;
    }
    __syncthreads();
    if (t < 2 * NL) {
        int which = (t >= NL) ? 1 : 0;
        int l = which ? (t - NL) : t;
        const float* er = enc + ((long long)b * NL + l) * ND2;
        const float* tc = tmpc[which];
        float acc = sb[which];
        for (int d = 0; d < 512; ++d) acc += er[d] * tc[d];
        if (which) da[l] = acc; else sa[l] = acc;
    }
    __syncthreads();
    int cd = cand[((long long)b * NS + s) * NC + t];
    float res = -1e9f;
    if (cd >= 0) {
        float acc = lfp[NF];
        const float* row = cemb + (long long)cd * 512;
        for (int d = 0; d < 512; ++d) acc += row[d] * oh[d];
        const float* fr = feats + (long long)cd * NF;
        for (int f = 0; f < NF; ++f) acc += fr[f] * lfp[f];
        int sc = osrc[cd];
        if (sc > 0) acc += sa[sc];
        int dc = odst[cd];
        if (dc > 0) acc += da[dc];
        res = acc;
    }
    out[(long long)NB * NS * 2 + ((long long)b * NS + s) * NC + t] = res;
}

extern "C" void kernel_launch(void* const* d_in, const int* in_sizes, int n_in,
                              void* d_out, int out_size, void* d_ws, size_t ws_size,
                              hipStream_t stream) {
    float* out = (float*)d_out;

    const float* enc         = (const float*)d_in[0];
    const int*   loc_idxs    = (const int*)d_in[1];
    const int*   cand        = (const int*)d_in[2];
    const int*   power       = (const int*)d_in[3];
    const int*   teacher     = (const int*)d_in[4];
    const float* MA          = (const float*)d_in[5];
    const float* order_emb_w = (const float*)d_in[6];
    const float* cand_emb_w  = (const float*)d_in[7];
    const float* plw         = (const float*)d_in[8];
    const float* plb         = (const float*)d_in[9];
    const float* w_ih0       = (const float*)d_in[10];
    const float* w_hh0       = (const float*)d_in[11];
    const float* b_ih0       = (const float*)d_in[12];
    const float* b_hh0       = (const float*)d_in[13];
    const float* w_ih1       = (const float*)d_in[14];
    const float* w_hh1       = (const float*)d_in[15];
    const float* b_ih1       = (const float*)d_in[16];
    const float* b_hh1       = (const float*)d_in[17];
    const float* ofeats      = (const float*)d_in[18];
    const float* ofl_w       = (const float*)d_in[19];
    const float* ofl_b       = (const float*)d_in[20];
    const float* odw_w       = (const float*)d_in[21];
    const float* odw_b       = (const float*)d_in[22];
    const float* odb_w       = (const float*)d_in[23];
    const float* odb_b       = (const float*)d_in[24];
    const float* rsw         = (const float*)d_in[25];
    const float* rsb         = (const float*)d_in[26];
    const float* rdw         = (const float*)d_in[27];
    const float* rdb         = (const float*)d_in[28];
    const float* esb         = (const float*)d_in[30];  // order_enc==0 -> only bias survives
    const float* edb         = (const float*)d_in[32];
    const int*   osrc        = (const int*)d_in[33];
    const int*   odst        = (const int*)d_in[34];

    float* ws = (float*)d_ws;
    float* xstat = ws + OFF_XSTAT;
    float* H0    = ws + OFF_H0;   // [2][512][64]
    float* c0T   = ws + OFF_C0;
    float* c1T   = ws + OFF_C1;
    float* OT    = ws + OFF_OT;   // [2][513][64]

    k_out01<<<5, 256, 0, stream>>>(cand, teacher, out);
    k_init<<<64, 256, 0, stream>>>(ws);
    k_locenc2<<<NB, 256, 0, stream>>>(loc_idxs, MA, enc, xstat);
    k_embpow<<<dim3(NS, NB), 256, 0, stream>>>(teacher, power, order_emb_w, ofeats,
                                               ofl_w, ofl_b, plw, plb, xstat);

    for (int s = 0; s < NS; ++s) {
        float* h0in   = H0 + (s & 1) * 32768;
        float* h0out  = H0 + ((s + 1) & 1) * 32768;
        float* otprev = OT + (s & 1) * 32832;
        float* otcur  = OT + ((s + 1) & 1) * 32832;
        // layer 0: x = [xstat[s] (652) ; h0_prev (512)]
        k_lstm<<<128, 512, 0, stream>>>(xstat + (long long)s * NKX * 64, NKX, h0in,
                                        w_ih0, w_hh0, b_ih0, b_hh0, c0T, h0out);
        // layer 1: x = [h0_new (512) ; h1_prev (512, rows 0-511 of otprev)]
        k_lstm<<<128, 512, 0, stream>>>(h0out, 512, otprev,
                                        w_ih1, w_hh1, b_ih1, b_hh1, c1T, otcur);
        // post: tmp gemms + fproj + srcadd + logits
        k_post<<<NB, 256, 0, stream>>>(otcur, enc, rsw, rsb, rdw, rdb, esb, edb,
                                       odw_w, odw_b, odb_w, odb_b,
                                       cand_emb_w, ofeats, cand, osrc, odst, s, out);
    }
}